// Round 7
// baseline (271.101 us; speedup 1.0000x reference)
//
#include <hip/hip_runtime.h>

// SpiralConv: g[t] = a*g[t-1] + init*x[t], g[-1]=last_conv; out = Re(g).
//   a = p/|p| * exp(-|p|).
// Fused single-kernel hierarchical chunked scan (CHUNK=16) with ONE grid
// barrier (was two):
//  - phase 2 is EMBEDDED in phase 1 via a last-arrival ticket: after a
//    block's S stores drain (vmcnt(0) at __syncthreads), its leader bumps a
//    per-(b,seg) monotonic counter; the 32nd arriver performs that segment's
//    chunk-scan itself (no waiting, dispatch-order-independent). Removes one
//    barrier AND the dedicated p2 window where 7/8 of the machine idled.
//  - Cross-block data (S, R, T) via relaxed AGENT-scope 8B atomics (sc1 ->
//    coherence point, bypasses non-coherent per-XCD L2) -> no fence storm.
//  - Barrier/ticket state: module-scope __device__ globals (zero at load,
//    never poisoned), monotonic generations -> no memset node, single graph
//    node.
//  - x timesteps 0-7 stashed in LDS in phase 1; 8-15 re-read from L3 in
//    phase 3 (issued before the T-scan so latency hides). Normal stores for
//    out (non-temporal stores REGRESSED: +39MB WRITE_SIZE, round 6).
// Grid = 1024 blocks x 256 thr = exactly 4 blocks/CU (launch_bounds(256,4),
// LDS 32 KiB <= 40 KiB/block) -> all co-resident -> spin barrier safe.

#define BB 4
#define LL 4096
#define DD 1024
#define CHUNK 16
#define KK 256     // LL/CHUNK
#define SEG 32     // chunks per segment
#define NSEG 8     // KK/SEG
#define NBLK 1024u

// ---- module-scope state: zero-init at load, monotonic forever ----
__device__ unsigned g_grp[32 * 32];    // barrier groups, stride 32 (128 B apart)
__device__ unsigned g_glob[32];        // barrier global, padded
__device__ unsigned g_seg[32 * 32];    // 32 per-(b,seg) tickets, stride 32

__device__ __forceinline__ void phazor_of(float pr, float pi, float& ar, float& ai) {
    float mag = sqrtf(pr * pr + pi * pi);
    float s = expf(-mag) / mag;   // phazor = p/|p| * exp(-|p|)
    ar = pr * s;
    ai = pi * s;
}

__device__ __forceinline__ void csq(float& r, float& i) {
    float nr = r * r - i * i;
    i = 2.f * r * i;
    r = nr;
}

// coherence-point (sc1) 8-byte data movement: visible cross-XCD without fences
__device__ __forceinline__ void st8(float2* p, float2 v) {
    __hip_atomic_store(p, v, __ATOMIC_RELAXED, __HIP_MEMORY_SCOPE_AGENT);
}
__device__ __forceinline__ float2 ld8(const float2* p) {
    return __hip_atomic_load((float2*)p, __ATOMIC_RELAXED, __HIP_MEMORY_SCOPE_AGENT);
}

// Fence-free monotonic grid barrier (single site per launch).
// __syncthreads() drains vmcnt -> all sc1 stores are at the coherence point
// before the leader's arrival add; consumers read via sc1 -> no staleness.
__device__ __forceinline__ void grid_barrier() {
    __syncthreads();
    if (threadIdx.x == 0) {
        unsigned* A = &g_grp[(blockIdx.x >> 5) * 32];   // 32 blocks per group
        unsigned* G = &g_glob[0];
        unsigned a = __hip_atomic_fetch_add(A, 1u,
                        __ATOMIC_RELAXED, __HIP_MEMORY_SCOPE_AGENT);
        unsigned gen = a >> 5;                          // which use (generation)
        if ((a & 31u) == 31u)
            __hip_atomic_fetch_add(G, 32u,
                        __ATOMIC_RELAXED, __HIP_MEMORY_SCOPE_AGENT);
        unsigned target = (gen + 1u) * NBLK;
        int spins = 0;
        while ((int)(__hip_atomic_load(G, __ATOMIC_RELAXED,
                                       __HIP_MEMORY_SCOPE_AGENT) - target) < 0) {
            __builtin_amdgcn_s_sleep(16);
            if (++spins > (1 << 17)) break;             // safety valve, never hang
        }
    }
    __syncthreads();
}

__global__ __launch_bounds__(256, 4) void spiral_fused(
    const float* __restrict__ x,
    const float* __restrict__ p_re, const float* __restrict__ p_im,
    const float* __restrict__ in_re, const float* __restrict__ in_im,
    const float* __restrict__ lc_re, const float* __restrict__ lc_im,
    float2* __restrict__ S, float2* __restrict__ R, float2* __restrict__ T,
    float* __restrict__ out)
{
    __shared__ float4 xlds[8][256];   // timesteps 0..7 stash, 32 KiB
    __shared__ int doP2;

    const int tid = blockIdx.x * 256 + threadIdx.x;
    const int dq = tid & (DD / 4 - 1);            // == threadIdx.x
    const int k  = (tid >> 8) & (KK - 1);         // block-uniform
    const int b  = tid >> 16;                     // block-uniform
    const int d0 = dq * 4;
    const int seg = k >> 5;                       // block-uniform
    const int rel = k & (SEG - 1);                // block-uniform

    // phase-invariant constants: a = phazor(p), binit
    float ar[4], ai[4], br[4], bi[4];
    {
        float4 prv = *(const float4*)(p_re + d0);
        float4 piv = *(const float4*)(p_im + d0);
        float4 brv = *(const float4*)(in_re + d0);
        float4 biv = *(const float4*)(in_im + d0);
        float prs[4] = {prv.x, prv.y, prv.z, prv.w};
        float pis[4] = {piv.x, piv.y, piv.z, piv.w};
        br[0] = brv.x; br[1] = brv.y; br[2] = brv.z; br[3] = brv.w;
        bi[0] = biv.x; bi[1] = biv.y; bi[2] = biv.z; bi[3] = biv.w;
#pragma unroll
        for (int q = 0; q < 4; ++q) phazor_of(prs[q], pis[q], ar[q], ai[q]);
    }

    const size_t xbase = (size_t)(b * LL + k * CHUNK) * DD + d0;

    // ---------------- phase 1: chunk-local scan, zero init ----------------
    {
        const float* xp = x + xbase;
        float4 xv[16];
#pragma unroll
        for (int j = 0; j < 16; ++j)
            xv[j] = *(const float4*)(xp + (size_t)j * DD);

        // stash first half for phase-3 replay (conflict-free: lane-contiguous)
#pragma unroll
        for (int j = 0; j < 8; ++j)
            xlds[j][threadIdx.x] = xv[j];

        float sr[4] = {0.f, 0.f, 0.f, 0.f};
        float si[4] = {0.f, 0.f, 0.f, 0.f};
#pragma unroll
        for (int j = 0; j < 16; ++j) {
            float xs[4] = {xv[j].x, xv[j].y, xv[j].z, xv[j].w};
#pragma unroll
            for (int q = 0; q < 4; ++q) {
                float nr = fmaf(ar[q], sr[q], fmaf(-ai[q], si[q], br[q] * xs[q]));
                float ni = fmaf(ar[q], si[q], fmaf( ai[q], sr[q], bi[q] * xs[q]));
                sr[q] = nr; si[q] = ni;
            }
        }
        float2* Sp = S + ((size_t)(b * KK + k) * DD + d0);
#pragma unroll
        for (int q = 0; q < 4; ++q)
            st8(Sp + q, make_float2(sr[q], si[q]));
    }

    // ---------------- embedded phase 2: last-arrival ticket ----------------
    __syncthreads();   // drains vmcnt(0): this block's S stores are at L3
    if (threadIdx.x == 0) {
        unsigned t = __hip_atomic_fetch_add(&g_seg[(b * NSEG + seg) * 32], 1u,
                        __ATOMIC_RELAXED, __HIP_MEMORY_SCOPE_AGENT);
        doP2 = ((t & 31u) == 31u);   // 32nd arriver: all segment S-stores drained
    }
    __syncthreads();

    if (doP2) {
        // this block scans its whole segment's chunk-totals (depth-2 pipeline)
        float q16r[4], q16i[4];
#pragma unroll
        for (int q = 0; q < 4; ++q) {
            q16r[q] = ar[q]; q16i[q] = ai[q];
#pragma unroll
            for (int i = 0; i < 4; ++i) csq(q16r[q], q16i[q]);   // a^16
        }
        const size_t segbase = (size_t)(b * KK + seg * SEG) * DD + d0;
        const float2* Sc = S + segbase;
        float2*       Rc = R + segbase;

        float cr[4] = {0,0,0,0}, ci[4] = {0,0,0,0};
        float2 bufA[4], bufB[4];
#pragma unroll
        for (int q = 0; q < 4; ++q) bufA[q] = ld8(Sc + q);
#pragma unroll
        for (int q = 0; q < 4; ++q) bufB[q] = ld8(Sc + DD + q);

#pragma unroll
        for (int kc = 0; kc < SEG; kc += 2) {
            // even step: consume bufA (chunk kc), prefetch chunk kc+2
#pragma unroll
            for (int q = 0; q < 4; ++q)
                st8(Rc + (size_t)kc * DD + q, make_float2(cr[q], ci[q]));
            {
                float2 s[4];
#pragma unroll
                for (int q = 0; q < 4; ++q) s[q] = bufA[q];
                if (kc + 2 < SEG) {
#pragma unroll
                    for (int q = 0; q < 4; ++q)
                        bufA[q] = ld8(Sc + (size_t)(kc + 2) * DD + q);
                }
#pragma unroll
                for (int q = 0; q < 4; ++q) {
                    float nr = fmaf(q16r[q], cr[q], fmaf(-q16i[q], ci[q], s[q].x));
                    float ni = fmaf(q16r[q], ci[q], fmaf( q16i[q], cr[q], s[q].y));
                    cr[q] = nr; ci[q] = ni;
                }
            }
            // odd step: consume bufB (chunk kc+1), prefetch chunk kc+3
#pragma unroll
            for (int q = 0; q < 4; ++q)
                st8(Rc + (size_t)(kc + 1) * DD + q, make_float2(cr[q], ci[q]));
            {
                float2 s[4];
#pragma unroll
                for (int q = 0; q < 4; ++q) s[q] = bufB[q];
                if (kc + 3 < SEG) {
#pragma unroll
                    for (int q = 0; q < 4; ++q)
                        bufB[q] = ld8(Sc + (size_t)(kc + 3) * DD + q);
                }
#pragma unroll
                for (int q = 0; q < 4; ++q) {
                    float nr = fmaf(q16r[q], cr[q], fmaf(-q16i[q], ci[q], s[q].x));
                    float ni = fmaf(q16r[q], ci[q], fmaf( q16i[q], cr[q], s[q].y));
                    cr[q] = nr; ci[q] = ni;
                }
            }
        }
#pragma unroll
        for (int q = 0; q < 4; ++q)
            st8(T + ((size_t)(b * NSEG + seg) * DD + d0 + q),
                make_float2(cr[q], ci[q]));
    }

    grid_barrier();   // the ONLY grid-wide barrier

    // ---------------- phase 3: segment init + combine + replay ----------------
    // issue second-half x loads + R loads NOW; latency hides under T-scan math
    float4 xv2[8];
    {
        const float* xp = x + xbase;
#pragma unroll
        for (int j = 0; j < 8; ++j)
            xv2[j] = *(const float4*)(xp + (size_t)(8 + j) * DD);
    }
    float2 rv[4];
    {
        const float2* Rp = R + ((size_t)(b * KK + k) * DD + d0);
#pragma unroll
        for (int q = 0; q < 4; ++q) rv[q] = ld8(Rp + q);
    }

    float gr[4], gi[4];
    {
        float4 lrv = *(const float4*)(lc_re + b * DD + d0);
        float4 liv = *(const float4*)(lc_im + b * DD + d0);
        gr[0] = lrv.x; gr[1] = lrv.y; gr[2] = lrv.z; gr[3] = lrv.w;
        gi[0] = liv.x; gi[1] = liv.y; gi[2] = liv.z; gi[3] = liv.w;
        float Qr[4], Qi[4];
#pragma unroll
        for (int q = 0; q < 4; ++q) {
            Qr[q] = ar[q]; Qi[q] = ai[q];
#pragma unroll
            for (int i = 0; i < 9; ++i) csq(Qr[q], Qi[q]);   // a^512
        }
        for (int s = 0; s < seg; ++s) {                      // <=7 iters, uniform
            const float2* Tp = T + ((size_t)(b * NSEG + s) * DD + d0);
#pragma unroll
            for (int q = 0; q < 4; ++q) {
                float2 t = ld8(Tp + q);
                float nr = fmaf(Qr[q], gr[q], fmaf(-Qi[q], gi[q], t.x));
                float ni = fmaf(Qr[q], gi[q], fmaf( Qi[q], gr[q], t.y));
                gr[q] = nr; gi[q] = ni;
            }
        }
    }

    // C0 = R + (a^16)^rel * g
    float cr[4], ci[4];
    {
#pragma unroll
        for (int q = 0; q < 4; ++q) {
            float qdr = ar[q], qdi = ai[q];
#pragma unroll
            for (int i = 0; i < 4; ++i) csq(qdr, qdi);       // a^16
            float pr = 1.f, pi = 0.f;
            float bpr = qdr, bpi = qdi;
#pragma unroll
            for (int bit = 0; bit < 5; ++bit) {              // (a^16)^rel
                if ((rel >> bit) & 1) {
                    float nr = pr * bpr - pi * bpi;
                    pi = pr * bpi + pi * bpr;
                    pr = nr;
                }
                csq(bpr, bpi);
            }
            cr[q] = rv[q].x + pr * gr[q] - pi * gi[q];
            ci[q] = rv[q].y + pr * gi[q] + pi * gr[q];
        }
    }

    // replay: timesteps 0..7 from LDS, 8..15 from the early global loads
    {
        float* op = out + xbase;
#pragma unroll
        for (int j = 0; j < 8; ++j) {
            float4 xj = xlds[j][threadIdx.x];
            float xs[4] = {xj.x, xj.y, xj.z, xj.w};
            float os[4];
#pragma unroll
            for (int q = 0; q < 4; ++q) {
                float nr = fmaf(ar[q], cr[q], fmaf(-ai[q], ci[q], br[q] * xs[q]));
                float ni = fmaf(ar[q], ci[q], fmaf( ai[q], cr[q], bi[q] * xs[q]));
                cr[q] = nr; ci[q] = ni;
                os[q] = nr;
            }
            *(float4*)(op + (size_t)j * DD) = make_float4(os[0], os[1], os[2], os[3]);
        }
#pragma unroll
        for (int j = 0; j < 8; ++j) {
            float xs[4] = {xv2[j].x, xv2[j].y, xv2[j].z, xv2[j].w};
            float os[4];
#pragma unroll
            for (int q = 0; q < 4; ++q) {
                float nr = fmaf(ar[q], cr[q], fmaf(-ai[q], ci[q], br[q] * xs[q]));
                float ni = fmaf(ar[q], ci[q], fmaf( ai[q], cr[q], bi[q] * xs[q]));
                cr[q] = nr; ci[q] = ni;
                os[q] = nr;
            }
            *(float4*)(op + (size_t)(8 + j) * DD) = make_float4(os[0], os[1], os[2], os[3]);
        }
    }
}

extern "C" void kernel_launch(void* const* d_in, const int* in_sizes, int n_in,
                              void* d_out, int out_size, void* d_ws, size_t ws_size,
                              hipStream_t stream) {
    const float* x      = (const float*)d_in[0];
    const float* p_re   = (const float*)d_in[1];
    const float* p_im   = (const float*)d_in[2];
    const float* pin_re = (const float*)d_in[3];
    const float* pin_im = (const float*)d_in[4];
    const float* lc_re  = (const float*)d_in[5];
    const float* lc_im  = (const float*)d_in[6];
    float* out = (float*)d_out;

    char* ws = (char*)d_ws;
    float2* S = (float2*)(ws);                              // 8 MiB
    float2* R = (float2*)(ws + (size_t)8  * 1024 * 1024);   // 8 MiB
    float2* T = (float2*)(ws + (size_t)16 * 1024 * 1024);   // 256 KiB

    // single kernel node: all sync state is module-scope + monotonic, no memset
    spiral_fused<<<dim3(NBLK), dim3(256), 0, stream>>>(
        x, p_re, p_im, pin_re, pin_im, lc_re, lc_im, S, R, T, out);
}

// Round 8
// 141.605 us; speedup vs baseline: 1.9145x; 1.9145x over previous
//
#include <hip/hip_runtime.h>

// SpiralConv: g[t] = a*g[t-1] + init*x[t], g[-1]=last_conv; out = Re(g).
//   a = p/|p| * exp(-|p|).
// 4-kernel hierarchical chunked scan (CHUNK=16, 256 chunks, 8 segments x 32).
// Structure = the proven 140.8us 3-kernel baseline + a tiny p2b kernel that
// hoists p3's serial segment-init chain (lc load + a^512 chain + <=7
// dependent L3 T-loads) out of every p3 block:
//   p1 : per (b,chunk,d)  local scan, zero init            -> S     (verbatim)
//   p2 : per (b,seg,d)    scan 32 chunks, zero init        -> R, T  (verbatim)
//   p2b: per (b,d)        8-step scan of T from lc         -> Gseg  (new, ~2us)
//   p3 : C0 = R + q^rel * Gseg[b][seg]; replay chunk       -> out
//        (loads issued BEFORE the C0 math; xhi issued before replay-lo)
// Dispatch-count is ~free (fixed ~50us/iter driver overhead measured across
// 2/3/4-dispatch variants in rounds 0-7); only sum-of-kernel-time matters.

#define BB 4
#define LL 4096
#define DD 1024
#define CHUNK 16
#define KK 256     // LL/CHUNK
#define SEG 32     // chunks per segment
#define NSEG 8     // KK/SEG

__device__ __forceinline__ void phazor_of(float pr, float pi, float& ar, float& ai) {
    float mag = sqrtf(pr * pr + pi * pi);
    float s = expf(-mag) / mag;   // phazor = p/|p| * exp(-|p|)
    ar = pr * s;
    ai = pi * s;
}

__device__ __forceinline__ void csq(float& r, float& i) {
    float nr = r * r - i * i;
    i = 2.f * r * i;
    r = nr;
}

// ---------------- p1: chunk-local scans (baseline, verbatim) ----------------
__global__ __launch_bounds__(256, 4) void spiral_p1(
    const float* __restrict__ x,
    const float* __restrict__ p_re, const float* __restrict__ p_im,
    const float* __restrict__ in_re, const float* __restrict__ in_im,
    float2* __restrict__ S)
{
    int tid = blockIdx.x * 256 + threadIdx.x;
    int dq = tid & (DD / 4 - 1);
    int k  = (tid >> 8) & (KK - 1);
    int b  = tid >> 16;
    int d0 = dq * 4;

    float4 prv = *(const float4*)(p_re + d0);
    float4 piv = *(const float4*)(p_im + d0);
    float4 brv = *(const float4*)(in_re + d0);
    float4 biv = *(const float4*)(in_im + d0);
    float ar[4], ai[4];
    float br[4] = {brv.x, brv.y, brv.z, brv.w};
    float bi[4] = {biv.x, biv.y, biv.z, biv.w};
    {
        float prs[4] = {prv.x, prv.y, prv.z, prv.w};
        float pis[4] = {piv.x, piv.y, piv.z, piv.w};
#pragma unroll
        for (int q = 0; q < 4; ++q) phazor_of(prs[q], pis[q], ar[q], ai[q]);
    }

    float sr[4] = {0.f, 0.f, 0.f, 0.f};
    float si[4] = {0.f, 0.f, 0.f, 0.f};
    const float* xp = x + ((size_t)(b * LL + k * CHUNK) * DD + d0);

#pragma unroll
    for (int t0 = 0; t0 < CHUNK; t0 += 8) {
        float4 xv[8];
#pragma unroll
        for (int j = 0; j < 8; ++j)
            xv[j] = *(const float4*)(xp + (size_t)(t0 + j) * DD);
#pragma unroll
        for (int j = 0; j < 8; ++j) {
            float xs[4] = {xv[j].x, xv[j].y, xv[j].z, xv[j].w};
#pragma unroll
            for (int q = 0; q < 4; ++q) {
                float nr = fmaf(ar[q], sr[q], fmaf(-ai[q], si[q], br[q] * xs[q]));
                float ni = fmaf(ar[q], si[q], fmaf( ai[q], sr[q], bi[q] * xs[q]));
                sr[q] = nr; si[q] = ni;
            }
        }
    }

    float4* Sp = (float4*)(S + ((size_t)(b * KK + k) * DD + d0));
    Sp[0] = make_float4(sr[0], si[0], sr[1], si[1]);
    Sp[1] = make_float4(sr[2], si[2], sr[3], si[3]);
}

// ---------------- p2: segment-relative scans (baseline, verbatim) ----------------
__global__ __launch_bounds__(128) void spiral_p2a(
    const float* __restrict__ p_re, const float* __restrict__ p_im,
    const float2* __restrict__ S,
    float2* __restrict__ R, float2* __restrict__ T)
{
    int gt  = blockIdx.x * 128 + threadIdx.x;
    int d   = gt & (DD - 1);
    int seg = (gt >> 10) & (NSEG - 1);
    int bb  = gt >> 13;

    float qr, qi;
    phazor_of(p_re[d], p_im[d], qr, qi);
#pragma unroll
    for (int i = 0; i < 4; ++i) csq(qr, qi);      // q = a^16

    const int kk0 = seg * SEG;
    const float2* Sc = S + ((size_t)bb * KK * DD + d);
    float2*       Rc = R + ((size_t)bb * KK * DD + d);

    float2 buf[8];
#pragma unroll
    for (int j = 0; j < 8; ++j) buf[j] = Sc[(size_t)(kk0 + j) * DD];

    float cr = 0.f, ci = 0.f;
    for (int i = 0; i < SEG; i += 8) {
#pragma unroll
        for (int j = 0; j < 8; ++j) {
            Rc[(size_t)(kk0 + i + j) * DD] = make_float2(cr, ci);
            float2 s = buf[j];
            int kn = i + j + 8;
            buf[j] = Sc[(size_t)(kk0 + (kn < SEG ? kn : SEG - 1)) * DD];
            float nr = fmaf(qr, cr, fmaf(-qi, ci, s.x));
            float ni = fmaf(qr, ci, fmaf( qi, cr, s.y));
            cr = nr; ci = ni;
        }
    }
    T[((size_t)bb * NSEG + seg) * DD + d] = make_float2(cr, ci);
}

// ---------------- p2b: per-(b,d) scan of segment totals from lc -> Gseg ----------------
// Gseg[b][seg][d] = state entering segment seg = lc scanned through T[0..seg-1]
// with Q = a^512. 4096 threads, 8 steps, T prefetched fully (independent loads).
__global__ __launch_bounds__(256) void spiral_p2b(
    const float* __restrict__ p_re, const float* __restrict__ p_im,
    const float* __restrict__ lc_re, const float* __restrict__ lc_im,
    const float2* __restrict__ T,
    float2* __restrict__ Gseg)
{
    int tid = blockIdx.x * 256 + threadIdx.x;   // 0..4095
    int d = tid & (DD - 1);
    int b = tid >> 10;

    // prefetch all 8 segment totals (independent addresses)
    float2 tv[NSEG];
#pragma unroll
    for (int s = 0; s < NSEG; ++s)
        tv[s] = T[((size_t)(b * NSEG + s)) * DD + d];

    float gr = lc_re[b * DD + d];
    float gi = lc_im[b * DD + d];

    float Qr, Qi;
    phazor_of(p_re[d], p_im[d], Qr, Qi);
#pragma unroll
    for (int i = 0; i < 9; ++i) csq(Qr, Qi);    // Q = a^512

#pragma unroll
    for (int s = 0; s < NSEG; ++s) {
        Gseg[((size_t)(b * NSEG + s)) * DD + d] = make_float2(gr, gi);
        float nr = fmaf(Qr, gr, fmaf(-Qi, gi, tv[s].x));
        float ni = fmaf(Qr, gi, fmaf( Qi, gr, tv[s].y));
        gr = nr; gi = ni;
    }
}

// ---------------- p3: combine + replay (loads hoisted ahead of math) ----------------
__global__ __launch_bounds__(256, 4) void spiral_p3(
    const float* __restrict__ x,
    const float* __restrict__ p_re, const float* __restrict__ p_im,
    const float* __restrict__ in_re, const float* __restrict__ in_im,
    const float2* __restrict__ R, const float2* __restrict__ Gseg,
    float* __restrict__ out)
{
    int tid = blockIdx.x * 256 + threadIdx.x;
    int dq = tid & (DD / 4 - 1);
    int k  = (tid >> 8) & (KK - 1);
    int b  = tid >> 16;
    int d0 = dq * 4;
    int rel = k & (SEG - 1);   // wave-uniform
    int seg = k >> 5;          // wave-uniform

    const size_t base = (size_t)(b * LL + k * CHUNK) * DD + d0;
    const float* xp = x + base;

    // ---- issue all prologue loads first: xlo[8], R, Gseg, params ----
    float4 xlo[8];
#pragma unroll
    for (int j = 0; j < 8; ++j)
        xlo[j] = *(const float4*)(xp + (size_t)j * DD);

    float2 rv[4], gs[4];
    {
        const float2* Rp = R    + ((size_t)(b * KK   + k  ) * DD + d0);
        const float2* Gp = Gseg + ((size_t)(b * NSEG + seg) * DD + d0);
#pragma unroll
        for (int q = 0; q < 4; ++q) rv[q] = Rp[q];
#pragma unroll
        for (int q = 0; q < 4; ++q) gs[q] = Gp[q];
    }

    float4 prv = *(const float4*)(p_re + d0);
    float4 piv = *(const float4*)(p_im + d0);
    float4 brv = *(const float4*)(in_re + d0);
    float4 biv = *(const float4*)(in_im + d0);

    // ---- VALU-only while loads are in flight: a, binit, q^rel ----
    float ar[4], ai[4];
    float br[4] = {brv.x, brv.y, brv.z, brv.w};
    float bi[4] = {biv.x, biv.y, biv.z, biv.w};
    {
        float prs[4] = {prv.x, prv.y, prv.z, prv.w};
        float pis[4] = {piv.x, piv.y, piv.z, piv.w};
#pragma unroll
        for (int q = 0; q < 4; ++q) phazor_of(prs[q], pis[q], ar[q], ai[q]);
    }

    // C0 = R + (a^16)^rel * Gseg
    float cr[4], ci[4];
    {
#pragma unroll
        for (int q = 0; q < 4; ++q) {
            float qdr = ar[q], qdi = ai[q];
#pragma unroll
            for (int i = 0; i < 4; ++i) csq(qdr, qdi);       // a^16
            float pr = 1.f, pi = 0.f;
            float bpr = qdr, bpi = qdi;
#pragma unroll
            for (int bit = 0; bit < 5; ++bit) {              // (a^16)^rel
                if ((rel >> bit) & 1) {
                    float nr = pr * bpr - pi * bpi;
                    pi = pr * bpi + pi * bpr;
                    pr = nr;
                }
                csq(bpr, bpi);
            }
            cr[q] = rv[q].x + pr * gs[q].x - pi * gs[q].y;
            ci[q] = rv[q].y + pr * gs[q].y + pi * gs[q].x;
        }
    }

    // issue second-half x loads before replay-lo consumes xlo
    float4 xhi[8];
#pragma unroll
    for (int j = 0; j < 8; ++j)
        xhi[j] = *(const float4*)(xp + (size_t)(8 + j) * DD);

    float* op = out + base;
#pragma unroll
    for (int j = 0; j < 8; ++j) {
        float xs[4] = {xlo[j].x, xlo[j].y, xlo[j].z, xlo[j].w};
        float os[4];
#pragma unroll
        for (int q = 0; q < 4; ++q) {
            float nr = fmaf(ar[q], cr[q], fmaf(-ai[q], ci[q], br[q] * xs[q]));
            float ni = fmaf(ar[q], ci[q], fmaf( ai[q], cr[q], bi[q] * xs[q]));
            cr[q] = nr; ci[q] = ni;
            os[q] = nr;
        }
        *(float4*)(op + (size_t)j * DD) = make_float4(os[0], os[1], os[2], os[3]);
    }
#pragma unroll
    for (int j = 0; j < 8; ++j) {
        float xs[4] = {xhi[j].x, xhi[j].y, xhi[j].z, xhi[j].w};
        float os[4];
#pragma unroll
        for (int q = 0; q < 4; ++q) {
            float nr = fmaf(ar[q], cr[q], fmaf(-ai[q], ci[q], br[q] * xs[q]));
            float ni = fmaf(ar[q], ci[q], fmaf( ai[q], cr[q], bi[q] * xs[q]));
            cr[q] = nr; ci[q] = ni;
            os[q] = nr;
        }
        *(float4*)(op + (size_t)(8 + j) * DD) = make_float4(os[0], os[1], os[2], os[3]);
    }
}

extern "C" void kernel_launch(void* const* d_in, const int* in_sizes, int n_in,
                              void* d_out, int out_size, void* d_ws, size_t ws_size,
                              hipStream_t stream) {
    const float* x      = (const float*)d_in[0];
    const float* p_re   = (const float*)d_in[1];
    const float* p_im   = (const float*)d_in[2];
    const float* pin_re = (const float*)d_in[3];
    const float* pin_im = (const float*)d_in[4];
    const float* lc_re  = (const float*)d_in[5];
    const float* lc_im  = (const float*)d_in[6];
    float* out = (float*)d_out;

    char* ws = (char*)d_ws;
    float2* S    = (float2*)(ws);                                   // 8 MiB
    float2* R    = (float2*)(ws + (size_t)8  * 1024 * 1024);        // 8 MiB
    float2* T    = (float2*)(ws + (size_t)16 * 1024 * 1024);        // 256 KiB
    float2* Gseg = (float2*)(ws + (size_t)16 * 1024 * 1024 + 256 * 1024); // 256 KiB

    spiral_p1 <<<dim3(1024), dim3(256), 0, stream>>>(x, p_re, p_im, pin_re, pin_im, S);
    spiral_p2a<<<dim3(256),  dim3(128), 0, stream>>>(p_re, p_im, S, R, T);
    spiral_p2b<<<dim3(16),   dim3(256), 0, stream>>>(p_re, p_im, lc_re, lc_im, T, Gseg);
    spiral_p3 <<<dim3(1024), dim3(256), 0, stream>>>(x, p_re, p_im, pin_re, pin_im,
                                                     R, Gseg, out);
}